// Round 1
// baseline (542.650 us; speedup 1.0000x reference)
//
#include <hip/hip_runtime.h>
#include <hip/hip_bf16.h>
#include <cmath>

// ---------------------------------------------------------------------------
// DistanceAwareSelfAttentionHead — f32 correctness-first implementation.
//
// Decomposition:
//   s_e   = sigmoid((attr_e - ib) * im)
//   bias_e = s*(q[src].Ek0) + (1-s)*(q[src].Ek1) + s*(k[dst].Eq0) + (1-s)*(k[dst].Eq1)
//   A      = 2*(q k^T);  A[src,dst] += bias_e (dup edges sum)
//   P      = softmax(A / sqrt(FEAT))
//   out    = P v + c0[i]*Ev0 + c1[i]*Ev1,  c0[i]=sum_{src=i} P_e s_e, c1 likewise
// ---------------------------------------------------------------------------

constexpr int BM = 64, BN = 64, BK = 16;

template<bool TB>
__global__ __launch_bounds__(256) void gemm_f32(
    const float* __restrict__ A, const float* __restrict__ B, float* __restrict__ C,
    int M, int N, int K, float alpha)
{
    __shared__ float As[BK][BM];
    __shared__ float Bs[BK][BN];
    const int bm = blockIdx.y * BM;
    const int bn = blockIdx.x * BN;
    const int tid = threadIdx.x;
    const int tx = tid & 15;   // n-direction
    const int ty = tid >> 4;   // m-direction
    float acc[4][4] = {};

    for (int k0 = 0; k0 < K; k0 += BK) {
        // A tile: 64 rows x 16 k, one float4 along K per thread
        {
            const int m  = tid >> 2;
            const int k4 = (tid & 3) * 4;
            const float4 av = *reinterpret_cast<const float4*>(&A[(size_t)(bm + m) * K + k0 + k4]);
            As[k4 + 0][m] = av.x; As[k4 + 1][m] = av.y;
            As[k4 + 2][m] = av.z; As[k4 + 3][m] = av.w;
        }
        if (TB) {
            // B is [N,K] row-major; Bs[k][n] = B[bn+n][k0+k]
            const int n  = tid >> 2;
            const int k4 = (tid & 3) * 4;
            const float4 bv = *reinterpret_cast<const float4*>(&B[(size_t)(bn + n) * K + k0 + k4]);
            Bs[k4 + 0][n] = bv.x; Bs[k4 + 1][n] = bv.y;
            Bs[k4 + 2][n] = bv.z; Bs[k4 + 3][n] = bv.w;
        } else {
            // B is [K,N] row-major; Bs[k][n] = B[k0+k][bn+n]
            const int kk = tid >> 4;
            const int n4 = (tid & 15) * 4;
            const float4 bv = *reinterpret_cast<const float4*>(&B[(size_t)(k0 + kk) * N + bn + n4]);
            Bs[kk][n4 + 0] = bv.x; Bs[kk][n4 + 1] = bv.y;
            Bs[kk][n4 + 2] = bv.z; Bs[kk][n4 + 3] = bv.w;
        }
        __syncthreads();
        #pragma unroll
        for (int kk = 0; kk < BK; ++kk) {
            const float4 av = *reinterpret_cast<const float4*>(&As[kk][ty * 4]);
            const float4 bv = *reinterpret_cast<const float4*>(&Bs[kk][tx * 4]);
            const float a[4] = {av.x, av.y, av.z, av.w};
            const float b[4] = {bv.x, bv.y, bv.z, bv.w};
            #pragma unroll
            for (int i = 0; i < 4; ++i)
                #pragma unroll
                for (int j = 0; j < 4; ++j)
                    acc[i][j] += a[i] * b[j];
        }
        __syncthreads();
    }
    #pragma unroll
    for (int i = 0; i < 4; ++i) {
        const int row = bm + ty * 4 + i;
        float4 o;
        o.x = acc[i][0] * alpha; o.y = acc[i][1] * alpha;
        o.z = acc[i][2] * alpha; o.w = acc[i][3] * alpha;
        *reinterpret_cast<float4*>(&C[(size_t)row * N + bn + tx * 4]) = o;
    }
}

// per-node dots: qk0[i]=q[i].Ek0, qk1[i]=q[i].Ek1, kq0[i]=k[i].Eq0, kq1[i]=k[i].Eq1
__global__ __launch_bounds__(256) void node_dots(
    const float* __restrict__ q, const float* __restrict__ k,
    const float* __restrict__ Ek, const float* __restrict__ Eq,
    float* qk0, float* qk1, float* kq0, float* kq1, int HID)
{
    const int node = blockIdx.x;
    const int t = threadIdx.x;   // == HID == 256
    const float qv = q[(size_t)node * HID + t];
    const float kv = k[(size_t)node * HID + t];
    float p0 = qv * Ek[t];
    float p1 = qv * Ek[HID + t];
    float p2 = kv * Eq[t];
    float p3 = kv * Eq[HID + t];
    #pragma unroll
    for (int off = 32; off > 0; off >>= 1) {
        p0 += __shfl_down(p0, off);
        p1 += __shfl_down(p1, off);
        p2 += __shfl_down(p2, off);
        p3 += __shfl_down(p3, off);
    }
    __shared__ float red[4][4];
    if ((t & 63) == 0) {
        const int w = t >> 6;
        red[w][0] = p0; red[w][1] = p1; red[w][2] = p2; red[w][3] = p3;
    }
    __syncthreads();
    if (t == 0) {
        qk0[node] = red[0][0] + red[1][0] + red[2][0] + red[3][0];
        qk1[node] = red[0][1] + red[1][1] + red[2][1] + red[3][1];
        kq0[node] = red[0][2] + red[1][2] + red[2][2] + red[3][2];
        kq1[node] = red[0][3] + red[1][3] + red[2][3] + red[3][3];
    }
}

__global__ void edge_bias_kernel(
    const int* __restrict__ ei, const float* __restrict__ attr,
    const float* __restrict__ qk0, const float* __restrict__ qk1,
    const float* __restrict__ kq0, const float* __restrict__ kq1,
    float* __restrict__ A, int E, int N,
    const float* __restrict__ ibp, const float* __restrict__ imp)
{
    const int e = blockIdx.x * blockDim.x + threadIdx.x;
    if (e >= E) return;
    const int src = ei[e];
    const int dst = ei[E + e];
    const float s = 1.f / (1.f + __expf(-(attr[e] - ibp[0]) * imp[0]));
    const float bias = s * qk0[src] + (1.f - s) * qk1[src]
                     + s * kq0[dst] + (1.f - s) * kq1[dst];
    atomicAdd(&A[(size_t)src * N + dst], bias);
}

// row softmax in-place; assumes N == 4096, 256 threads (16 elems/thread)
__global__ __launch_bounds__(256) void softmax_rows(float* __restrict__ A, int N, float scale)
{
    const int row = blockIdx.x;
    float* a = A + (size_t)row * N;
    const int t = threadIdx.x;
    float4 vals[4];
    float mx = -1e30f;
    #pragma unroll
    for (int u = 0; u < 4; ++u) {
        float4 vv = reinterpret_cast<float4*>(a)[t + u * 256];
        vv.x *= scale; vv.y *= scale; vv.z *= scale; vv.w *= scale;
        vals[u] = vv;
        mx = fmaxf(mx, fmaxf(fmaxf(vv.x, vv.y), fmaxf(vv.z, vv.w)));
    }
    __shared__ float red[4];
    #pragma unroll
    for (int off = 32; off > 0; off >>= 1) mx = fmaxf(mx, __shfl_down(mx, off));
    if ((t & 63) == 0) red[t >> 6] = mx;
    __syncthreads();
    const float m = fmaxf(fmaxf(red[0], red[1]), fmaxf(red[2], red[3]));
    __syncthreads();
    float sum = 0.f;
    #pragma unroll
    for (int u = 0; u < 4; ++u) {
        vals[u].x = __expf(vals[u].x - m);
        vals[u].y = __expf(vals[u].y - m);
        vals[u].z = __expf(vals[u].z - m);
        vals[u].w = __expf(vals[u].w - m);
        sum += vals[u].x + vals[u].y + vals[u].z + vals[u].w;
    }
    #pragma unroll
    for (int off = 32; off > 0; off >>= 1) sum += __shfl_down(sum, off);
    if ((t & 63) == 0) red[t >> 6] = sum;
    __syncthreads();
    const float inv = 1.f / (red[0] + red[1] + red[2] + red[3]);
    #pragma unroll
    for (int u = 0; u < 4; ++u) {
        float4 vv = vals[u];
        vv.x *= inv; vv.y *= inv; vv.z *= inv; vv.w *= inv;
        reinterpret_cast<float4*>(a)[t + u * 256] = vv;
    }
}

__global__ void zero_kernel(float* __restrict__ p, int n)
{
    const int i = blockIdx.x * blockDim.x + threadIdx.x;
    if (i < n) p[i] = 0.f;
}

__global__ void edge_coeff_kernel(
    const int* __restrict__ ei, const float* __restrict__ attr,
    const float* __restrict__ A, float* __restrict__ c0, float* __restrict__ c1,
    int E, int N, const float* __restrict__ ibp, const float* __restrict__ imp)
{
    const int e = blockIdx.x * blockDim.x + threadIdx.x;
    if (e >= E) return;
    const int src = ei[e];
    const int dst = ei[E + e];
    const float s = 1.f / (1.f + __expf(-(attr[e] - ibp[0]) * imp[0]));
    const float p = A[(size_t)src * N + dst];
    atomicAdd(&c0[src], p * s);
    atomicAdd(&c1[src], p * (1.f - s));
}

__global__ void add_rv_kernel(
    float* __restrict__ out, const float* __restrict__ c0, const float* __restrict__ c1,
    const float* __restrict__ Ev, int FEAT)
{
    const int idx = blockIdx.x * blockDim.x + threadIdx.x;
    const int i = idx / FEAT;
    const int f = idx % FEAT;
    out[idx] += c0[i] * Ev[f] + c1[i] * Ev[FEAT + f];
}

extern "C" void kernel_launch(void* const* d_in, const int* in_sizes, int n_in,
                              void* d_out, int out_size, void* d_ws, size_t ws_size,
                              hipStream_t stream)
{
    const float* x    = (const float*)d_in[0];
    const int*   ei   = (const int*)d_in[1];
    const float* attr = (const float*)d_in[2];
    const float* Wk   = (const float*)d_in[3];
    const float* Wq   = (const float*)d_in[4];
    const float* Wv   = (const float*)d_in[5];
    const float* Ek   = (const float*)d_in[6];
    const float* Eq   = (const float*)d_in[7];
    const float* Ev   = (const float*)d_in[8];
    const float* ib   = (const float*)d_in[9];
    const float* im   = (const float*)d_in[10];
    float* out = (float*)d_out;

    const int FEAT = (int)lroundf(sqrtf((float)in_sizes[5]));   // 512
    const int HID  = in_sizes[3] / FEAT;                         // 256
    const int N    = in_sizes[0] / FEAT;                         // 4096
    const int E    = in_sizes[2];                                // 131072

    float* ws = (float*)d_ws;
    size_t o = 0;
    float* q    = ws + o; o += (size_t)N * HID;
    float* kbuf = ws + o; o += (size_t)N * HID;
    float* v    = ws + o; o += (size_t)N * FEAT;
    float* Abuf = ws + o; o += (size_t)N * N;
    float* qk0  = ws + o; o += N;
    float* qk1  = ws + o; o += N;
    float* kq0  = ws + o; o += N;
    float* kq1  = ws + o; o += N;
    float* c0   = ws + o; o += N;
    float* c1   = ws + o; o += N;   // c0,c1 contiguous

    const dim3 blk(256);

    // q, k, v projections
    gemm_f32<false><<<dim3(HID / BN, N / BM), blk, 0, stream>>>(x, Wq, q,    N, HID,  FEAT, 1.f);
    gemm_f32<false><<<dim3(HID / BN, N / BM), blk, 0, stream>>>(x, Wk, kbuf, N, HID,  FEAT, 1.f);
    gemm_f32<false><<<dim3(FEAT / BN, N / BM), blk, 0, stream>>>(x, Wv, v,   N, FEAT, FEAT, 1.f);

    // per-node embedding dots
    node_dots<<<N, HID, 0, stream>>>(q, kbuf, Ek, Eq, qk0, qk1, kq0, kq1, HID);

    // A = 2 * q k^T
    gemm_f32<true><<<dim3(N / BN, N / BM), blk, 0, stream>>>(q, kbuf, Abuf, N, N, HID, 2.f);

    // += per-edge bias (duplicates sum)
    edge_bias_kernel<<<(E + 255) / 256, blk, 0, stream>>>(ei, attr, qk0, qk1, kq0, kq1,
                                                          Abuf, E, N, ib, im);

    // row softmax with 1/sqrt(FEAT) scale
    softmax_rows<<<N, blk, 0, stream>>>(Abuf, N, 1.f / sqrtf((float)FEAT));

    // edge coefficients c0, c1
    zero_kernel<<<(2 * N + 255) / 256, blk, 0, stream>>>(c0, 2 * N);
    edge_coeff_kernel<<<(E + 255) / 256, blk, 0, stream>>>(ei, attr, Abuf, c0, c1, E, N, ib, im);

    // out = P @ v
    gemm_f32<false><<<dim3(FEAT / BN, N / BM), blk, 0, stream>>>(Abuf, v, out, N, FEAT, N, 1.f);

    // out += c0[i]*Ev0 + c1[i]*Ev1
    add_rv_kernel<<<((size_t)N * FEAT + 255) / 256, blk, 0, stream>>>(out, c0, c1, Ev, FEAT);
}

// Round 2
// 221.104 us; speedup vs baseline: 2.4543x; 2.4543x over previous
//
#include <hip/hip_runtime.h>
#include <hip/hip_bf16.h>
#include <cmath>

// ---------------------------------------------------------------------------
// DistanceAwareSelfAttentionHead — bf16 MFMA version.
//   s_e    = sigmoid((attr_e - ib) * im)
//   bias_e = s*(q[src].Ek0)+(1-s)*(q[src].Ek1)+s*(k[dst].Eq0)+(1-s)*(k[dst].Eq1)
//   A      = 2*(q k^T) (f32);  A[src,dst] += bias_e
//   P      = softmax(A / sqrt(FEAT))  -> stored bf16
//   out    = P v + c0[i]*Ev0 + c1[i]*Ev1
// GEMMs on matrix cores (16x16x32 bf16, 128x128 tile, global_load_lds w=16).
// ---------------------------------------------------------------------------

typedef short bf16x8 __attribute__((ext_vector_type(8)));
typedef float f32x4  __attribute__((ext_vector_type(4)));
typedef unsigned short ushort_t;
typedef unsigned short ushort4v __attribute__((ext_vector_type(4)));
typedef unsigned short ushort8v __attribute__((ext_vector_type(8)));

__device__ __forceinline__ ushort_t f2bf(float f) {
    union { float f; unsigned u; } v; v.f = f;
    unsigned u = v.u;
    u += 0x7FFFu + ((u >> 16) & 1u);   // RNE
    return (ushort_t)(u >> 16);
}
__device__ __forceinline__ float bf2f(ushort_t h) {
    union { unsigned u; float f; } v; v.u = ((unsigned)h) << 16;
    return v.f;
}
__device__ __forceinline__ void gload_lds16(const void* g, void* l) {
    __builtin_amdgcn_global_load_lds(
        (const __attribute__((address_space(1))) void*)g,
        (__attribute__((address_space(3))) void*)l, 16, 0, 0);
}

// ---------------------------------------------------------------------------
// NT bf16 GEMM: C[m][n] = alpha * sum_k A[m][k] * B[n][k]
// A:[M,K] bf16, B:[N,K] bf16. M,N mult of 128, K mult of 32.
// ---------------------------------------------------------------------------
template<bool STORE_BF16>
__global__ __launch_bounds__(256) void gemm_nt_mfma(
    const ushort_t* __restrict__ A, const ushort_t* __restrict__ B,
    void* __restrict__ Cv, int M, int N, int K, float alpha)
{
    constexpr int BM = 128, BN = 128, BK = 32;
    __shared__ ushort_t As[BM * BK];   // 8 KB, linear (global_load_lds layout)
    __shared__ ushort_t Bs[BN * BK];   // 8 KB

    const int tid  = threadIdx.x;
    const int lane = tid & 63;
    const int wid  = tid >> 6;
    const int bm = blockIdx.y * BM;
    const int bn = blockIdx.x * BN;
    const int wm = (wid >> 1) * 64;    // wave 2x2 -> 64x64 each
    const int wn = (wid & 1) * 64;

    f32x4 acc[4][4] = {};

    // staging: chunk c (= h*256 + tid) covers tile row c>>2, k-col (c&3)*8
    const int r0 = tid >> 2;
    const int c8 = (tid & 3) * 8;
    const ushort_t* Ag0 = A + (size_t)(bm + r0) * K + c8;
    const ushort_t* Bg0 = B + (size_t)(bn + r0) * K + c8;
    const ushort_t* Ag1 = Ag0 + (size_t)64 * K;
    const ushort_t* Bg1 = Bg0 + (size_t)64 * K;
    ushort_t* AsW0 = &As[(wid * 64) * 8];          // wave-uniform LDS bases
    ushort_t* AsW1 = &As[(256 + wid * 64) * 8];
    ushort_t* BsW0 = &Bs[(wid * 64) * 8];
    ushort_t* BsW1 = &Bs[(256 + wid * 64) * 8];

    const int fr = lane & 15;          // fragment row/col within 16
    const int kh = (lane >> 4) * 8;    // k offset within BK

    for (int k0 = 0; k0 < K; k0 += BK) {
        gload_lds16(Ag0 + k0, AsW0);
        gload_lds16(Ag1 + k0, AsW1);
        gload_lds16(Bg0 + k0, BsW0);
        gload_lds16(Bg1 + k0, BsW1);
        __syncthreads();               // drains vmcnt before barrier

        bf16x8 af[4], bfv[4];
        #pragma unroll
        for (int i = 0; i < 4; ++i) {
            af[i]  = *(const bf16x8*)&As[(wm + i * 16 + fr) * BK + kh];
            bfv[i] = *(const bf16x8*)&Bs[(wn + i * 16 + fr) * BK + kh];
        }
        #pragma unroll
        for (int i = 0; i < 4; ++i)
            #pragma unroll
            for (int j = 0; j < 4; ++j)
                acc[i][j] = __builtin_amdgcn_mfma_f32_16x16x32_bf16(
                    af[i], bfv[j], acc[i][j], 0, 0, 0);
        __syncthreads();
    }

    // C/D layout: col = lane&15, row = (lane>>4)*4 + reg  [m89-verified]
    const int cr = (lane >> 4) * 4;
    const int cc = lane & 15;
    #pragma unroll
    for (int i = 0; i < 4; ++i)
        #pragma unroll
        for (int j = 0; j < 4; ++j) {
            const int col = bn + wn + j * 16 + cc;
            const int rowb = bm + wm + i * 16 + cr;
            #pragma unroll
            for (int jj = 0; jj < 4; ++jj) {
                const float val = alpha * acc[i][j][jj];
                if (STORE_BF16)
                    ((ushort_t*)Cv)[(size_t)(rowb + jj) * N + col] = f2bf(val);
                else
                    ((float*)Cv)[(size_t)(rowb + jj) * N + col] = val;
            }
        }
}

// ---------------------------------------------------------------------------
__global__ void f32_to_bf16_vec(const float* __restrict__ in,
                                ushort_t* __restrict__ out, int n8)
{
    const int i = blockIdx.x * 256 + threadIdx.x;
    if (i >= n8) return;
    const float4 a = ((const float4*)in)[2 * i];
    const float4 b = ((const float4*)in)[2 * i + 1];
    ushort8v o;
    o[0] = f2bf(a.x); o[1] = f2bf(a.y); o[2] = f2bf(a.z); o[3] = f2bf(a.w);
    o[4] = f2bf(b.x); o[5] = f2bf(b.y); o[6] = f2bf(b.z); o[7] = f2bf(b.w);
    ((ushort8v*)out)[i] = o;
}

// W[K][O] (f32) -> Wt[O][K] (bf16)
__global__ void transpose_to_bf16(const float* __restrict__ W,
                                  ushort_t* __restrict__ Wt, int K, int O)
{
    const int idx = blockIdx.x * 256 + threadIdx.x;
    if (idx >= K * O) return;
    const int i = idx % K;
    const int o = idx / K;
    Wt[idx] = f2bf(W[(size_t)i * O + o]);
}

// per-node dots: qk0[i]=q[i].Ek0, qk1[i]=q[i].Ek1, kq0[i]=k[i].Eq0, kq1[i]=k[i].Eq1
__global__ __launch_bounds__(256) void node_dots(
    const ushort_t* __restrict__ q, const ushort_t* __restrict__ k,
    const float* __restrict__ Ek, const float* __restrict__ Eq,
    float* qk0, float* qk1, float* kq0, float* kq1, int HID)
{
    const int node = blockIdx.x;
    const int t = threadIdx.x;   // == HID == 256
    const float qv = bf2f(q[(size_t)node * HID + t]);
    const float kv = bf2f(k[(size_t)node * HID + t]);
    float p0 = qv * Ek[t];
    float p1 = qv * Ek[HID + t];
    float p2 = kv * Eq[t];
    float p3 = kv * Eq[HID + t];
    #pragma unroll
    for (int off = 32; off > 0; off >>= 1) {
        p0 += __shfl_down(p0, off);
        p1 += __shfl_down(p1, off);
        p2 += __shfl_down(p2, off);
        p3 += __shfl_down(p3, off);
    }
    __shared__ float red[4][4];
    if ((t & 63) == 0) {
        const int w = t >> 6;
        red[w][0] = p0; red[w][1] = p1; red[w][2] = p2; red[w][3] = p3;
    }
    __syncthreads();
    if (t == 0) {
        qk0[node] = red[0][0] + red[1][0] + red[2][0] + red[3][0];
        qk1[node] = red[0][1] + red[1][1] + red[2][1] + red[3][1];
        kq0[node] = red[0][2] + red[1][2] + red[2][2] + red[3][2];
        kq1[node] = red[0][3] + red[1][3] + red[2][3] + red[3][3];
    }
}

__global__ void edge_bias_kernel(
    const int* __restrict__ ei, const float* __restrict__ attr,
    const float* __restrict__ qk0, const float* __restrict__ qk1,
    const float* __restrict__ kq0, const float* __restrict__ kq1,
    float* __restrict__ A, int E, int N,
    const float* __restrict__ ibp, const float* __restrict__ imp)
{
    const int e = blockIdx.x * blockDim.x + threadIdx.x;
    if (e >= E) return;
    const int src = ei[e];
    const int dst = ei[E + e];
    const float s = 1.f / (1.f + __expf(-(attr[e] - ibp[0]) * imp[0]));
    const float bias = s * qk0[src] + (1.f - s) * qk1[src]
                     + s * kq0[dst] + (1.f - s) * kq1[dst];
    atomicAdd(&A[(size_t)src * N + dst], bias);
}

// row softmax: read f32 logits, write bf16 probs. N==4096, 256 threads.
__global__ __launch_bounds__(256) void softmax_rows_bf16(
    const float* __restrict__ A, ushort_t* __restrict__ P, int N, float scale)
{
    const int row = blockIdx.x;
    const float* a = A + (size_t)row * N;
    ushort_t* p = P + (size_t)row * N;
    const int t = threadIdx.x;
    float4 vals[4];
    float mx = -1e30f;
    #pragma unroll
    for (int u = 0; u < 4; ++u) {
        float4 vv = ((const float4*)a)[t + u * 256];
        vv.x *= scale; vv.y *= scale; vv.z *= scale; vv.w *= scale;
        vals[u] = vv;
        mx = fmaxf(mx, fmaxf(fmaxf(vv.x, vv.y), fmaxf(vv.z, vv.w)));
    }
    __shared__ float red[4];
    #pragma unroll
    for (int off = 32; off > 0; off >>= 1) mx = fmaxf(mx, __shfl_down(mx, off));
    if ((t & 63) == 0) red[t >> 6] = mx;
    __syncthreads();
    const float m = fmaxf(fmaxf(red[0], red[1]), fmaxf(red[2], red[3]));
    __syncthreads();
    float sum = 0.f;
    #pragma unroll
    for (int u = 0; u < 4; ++u) {
        vals[u].x = __expf(vals[u].x - m);
        vals[u].y = __expf(vals[u].y - m);
        vals[u].z = __expf(vals[u].z - m);
        vals[u].w = __expf(vals[u].w - m);
        sum += vals[u].x + vals[u].y + vals[u].z + vals[u].w;
    }
    #pragma unroll
    for (int off = 32; off > 0; off >>= 1) sum += __shfl_down(sum, off);
    if ((t & 63) == 0) red[t >> 6] = sum;
    __syncthreads();
    const float inv = 1.f / (red[0] + red[1] + red[2] + red[3]);
    #pragma unroll
    for (int u = 0; u < 4; ++u) {
        ushort4v o;
        o[0] = f2bf(vals[u].x * inv);
        o[1] = f2bf(vals[u].y * inv);
        o[2] = f2bf(vals[u].z * inv);
        o[3] = f2bf(vals[u].w * inv);
        ((ushort4v*)p)[t + u * 256] = o;
    }
}

__global__ void zero_kernel(float* __restrict__ p, int n)
{
    const int i = blockIdx.x * blockDim.x + threadIdx.x;
    if (i < n) p[i] = 0.f;
}

__global__ void edge_coeff_kernel(
    const int* __restrict__ ei, const float* __restrict__ attr,
    const ushort_t* __restrict__ P, float* __restrict__ c0, float* __restrict__ c1,
    int E, int N, const float* __restrict__ ibp, const float* __restrict__ imp)
{
    const int e = blockIdx.x * blockDim.x + threadIdx.x;
    if (e >= E) return;
    const int src = ei[e];
    const int dst = ei[E + e];
    const float s = 1.f / (1.f + __expf(-(attr[e] - ibp[0]) * imp[0]));
    const float pv = bf2f(P[(size_t)src * N + dst]);
    atomicAdd(&c0[src], pv * s);
    atomicAdd(&c1[src], pv * (1.f - s));
}

__global__ void add_rv_kernel(
    float* __restrict__ out, const float* __restrict__ c0,
    const float* __restrict__ c1, const float* __restrict__ Ev, int FEAT)
{
    const int idx = blockIdx.x * blockDim.x + threadIdx.x;
    const int i = idx / FEAT;
    const int f = idx % FEAT;
    out[idx] += c0[i] * Ev[f] + c1[i] * Ev[FEAT + f];
}

// ---------------------------------------------------------------------------
extern "C" void kernel_launch(void* const* d_in, const int* in_sizes, int n_in,
                              void* d_out, int out_size, void* d_ws, size_t ws_size,
                              hipStream_t stream)
{
    const float* x    = (const float*)d_in[0];
    const int*   ei   = (const int*)d_in[1];
    const float* attr = (const float*)d_in[2];
    const float* Wk   = (const float*)d_in[3];
    const float* Wq   = (const float*)d_in[4];
    const float* Wv   = (const float*)d_in[5];
    const float* Ek   = (const float*)d_in[6];
    const float* Eq   = (const float*)d_in[7];
    const float* Ev   = (const float*)d_in[8];
    const float* ib   = (const float*)d_in[9];
    const float* im   = (const float*)d_in[10];
    float* out = (float*)d_out;

    const int FEAT = (int)lroundf(sqrtf((float)in_sizes[5]));   // 512
    const int HID  = in_sizes[3] / FEAT;                        // 256
    const int N    = in_sizes[0] / FEAT;                        // 4096
    const int E    = in_sizes[2];                               // 131072

    char* w = (char*)d_ws;
    size_t o = 0;
    ushort_t* xb  = (ushort_t*)(w + o); o += (size_t)N * FEAT * 2;     // 4 MB
    ushort_t* Wqt = (ushort_t*)(w + o); o += (size_t)HID * FEAT * 2;   // 256 KB
    ushort_t* Wkt = (ushort_t*)(w + o); o += (size_t)HID * FEAT * 2;
    ushort_t* Wvt = (ushort_t*)(w + o); o += (size_t)FEAT * FEAT * 2;  // 512 KB
    ushort_t* qb  = (ushort_t*)(w + o); o += (size_t)N * HID * 2;      // 2 MB
    ushort_t* kb  = (ushort_t*)(w + o); o += (size_t)N * HID * 2;
    ushort_t* vTb = (ushort_t*)(w + o); o += (size_t)FEAT * N * 2;     // 4 MB
    float*    Abuf= (float*)(w + o);    o += (size_t)N * N * 4;        // 64 MB
    ushort_t* Pb  = (ushort_t*)(w + o); o += (size_t)N * N * 2;        // 32 MB
    float*    qk0 = (float*)(w + o);    o += (size_t)N * 4;
    float*    qk1 = (float*)(w + o);    o += (size_t)N * 4;
    float*    kq0 = (float*)(w + o);    o += (size_t)N * 4;
    float*    kq1 = (float*)(w + o);    o += (size_t)N * 4;
    float*    c0  = (float*)(w + o);    o += (size_t)N * 4;
    float*    c1  = (float*)(w + o);    o += (size_t)N * 4;   // contiguous w/ c0

    const dim3 blk(256);

    // bf16 conversions
    f32_to_bf16_vec<<<(N * FEAT / 8 + 255) / 256, blk, 0, stream>>>(x, xb, N * FEAT / 8);
    transpose_to_bf16<<<(FEAT * HID + 255) / 256, blk, 0, stream>>>(Wq, Wqt, FEAT, HID);
    transpose_to_bf16<<<(FEAT * HID + 255) / 256, blk, 0, stream>>>(Wk, Wkt, FEAT, HID);
    transpose_to_bf16<<<(FEAT * FEAT + 255) / 256, blk, 0, stream>>>(Wv, Wvt, FEAT, FEAT);

    // projections: qb = xb Wqt^T, kb = xb Wkt^T, vTb = Wvt xb^T
    gemm_nt_mfma<true><<<dim3(HID / 128, N / 128), blk, 0, stream>>>(xb, Wqt, qb, N, HID, FEAT, 1.f);
    gemm_nt_mfma<true><<<dim3(HID / 128, N / 128), blk, 0, stream>>>(xb, Wkt, kb, N, HID, FEAT, 1.f);
    gemm_nt_mfma<true><<<dim3(N / 128, FEAT / 128), blk, 0, stream>>>(Wvt, xb, vTb, FEAT, N, FEAT, 1.f);

    // per-node embedding dots (from bf16 q,k)
    node_dots<<<N, blk, 0, stream>>>(qb, kb, Ek, Eq, qk0, qk1, kq0, kq1, HID);

    // A = 2 * q k^T  (f32)
    gemm_nt_mfma<false><<<dim3(N / 128, N / 128), blk, 0, stream>>>(qb, kb, Abuf, N, N, HID, 2.f);

    // += per-edge bias
    edge_bias_kernel<<<(E + 255) / 256, blk, 0, stream>>>(ei, attr, qk0, qk1, kq0, kq1,
                                                          Abuf, E, N, ib, im);

    // P = softmax(A / sqrt(FEAT)) -> bf16
    softmax_rows_bf16<<<N, blk, 0, stream>>>(Abuf, Pb, N, 1.f / sqrtf((float)FEAT));

    // edge coefficients
    zero_kernel<<<(2 * N + 255) / 256, blk, 0, stream>>>(c0, 2 * N);
    edge_coeff_kernel<<<(E + 255) / 256, blk, 0, stream>>>(ei, attr, Pb, c0, c1, E, N, ib, im);

    // out = P @ v   (A = Pb [N,N], B = vTb [FEAT,N])
    gemm_nt_mfma<false><<<dim3(FEAT / 128, N / 128), blk, 0, stream>>>(Pb, vTb, out, N, FEAT, N, 1.f);

    // out += c0[i]*Ev0 + c1[i]*Ev1
    add_rv_kernel<<<((N * FEAT) + 255) / 256, blk, 0, stream>>>(out, c0, c1, Ev, FEAT);
}

// Round 3
// 154.349 us; speedup vs baseline: 3.5157x; 1.4325x over previous
//
#include <hip/hip_runtime.h>
#include <hip/hip_bf16.h>
#include <cmath>

// ---------------------------------------------------------------------------
// DistanceAwareSelfAttentionHead — bf16 MFMA, round 3.
//   - split-K P@V (partials alias dead Abuf), reduce fused into epilogue
//   - merged q/k projection GEMM
//   - XCD-aware block swizzle on GEMMs
// ---------------------------------------------------------------------------

typedef short bf16x8 __attribute__((ext_vector_type(8)));
typedef float f32x4  __attribute__((ext_vector_type(4)));
typedef unsigned short ushort_t;
typedef unsigned short ushort4v __attribute__((ext_vector_type(4)));
typedef unsigned short ushort8v __attribute__((ext_vector_type(8)));

__device__ __forceinline__ ushort_t f2bf(float f) {
    union { float f; unsigned u; } v; v.f = f;
    unsigned u = v.u;
    u += 0x7FFFu + ((u >> 16) & 1u);   // RNE
    return (ushort_t)(u >> 16);
}
__device__ __forceinline__ float bf2f(ushort_t h) {
    union { unsigned u; float f; } v; v.u = ((unsigned)h) << 16;
    return v.f;
}
__device__ __forceinline__ void gload_lds16(const void* g, void* l) {
    __builtin_amdgcn_global_load_lds(
        (const __attribute__((address_space(1))) void*)g,
        (__attribute__((address_space(3))) void*)l, 16, 0, 0);
}

// ---------------------------------------------------------------------------
// NT bf16 GEMM: C[m][n] = alpha * sum_{k in chunk z} A[m][k] * B[n][k]
// A row-stride lda, B row-stride ldb, C row-stride ldc.
// Grid: (x = N/128, y = M/128, z = k-chunks). Chunk z covers k in
// [z*Ksz, (z+1)*Ksz); C written at Cv + z*zstride (f32) or bf16 when z==0 only.
// ---------------------------------------------------------------------------
template<bool STORE_BF16>
__global__ __launch_bounds__(256) void gemm_nt_mfma(
    const ushort_t* __restrict__ A, const ushort_t* __restrict__ B,
    void* __restrict__ Cv, int lda, int ldb, int ldc,
    int Ksz, float alpha, size_t zstride)
{
    constexpr int BK = 32;
    __shared__ ushort_t As[128 * BK];   // 8 KB, linear (global_load_lds layout)
    __shared__ ushort_t Bs[128 * BK];   // 8 KB

    // XCD-aware bijective swizzle of the xy-plane (grid xy always %8==0 here)
    int bid = blockIdx.y * gridDim.x + blockIdx.x;
    const int nwg = gridDim.x * gridDim.y;
    if ((nwg & 7) == 0) {
        const int cpx = nwg >> 3;
        bid = (bid & 7) * cpx + (bid >> 3);
    }
    const int bm = (bid / gridDim.x) * 128;
    const int bn = (bid % gridDim.x) * 128;

    const int tid  = threadIdx.x;
    const int lane = tid & 63;
    const int wid  = tid >> 6;
    const int wm = (wid >> 1) * 64;    // wave 2x2 -> 64x64 each
    const int wn = (wid & 1) * 64;

    f32x4 acc[4][4] = {};

    const int r0 = tid >> 2;
    const int c8 = (tid & 3) * 8;
    const size_t kbase = (size_t)blockIdx.z * Ksz;
    const ushort_t* Ag0 = A + (size_t)(bm + r0) * lda + kbase + c8;
    const ushort_t* Bg0 = B + (size_t)(bn + r0) * ldb + kbase + c8;
    const ushort_t* Ag1 = Ag0 + (size_t)64 * lda;
    const ushort_t* Bg1 = Bg0 + (size_t)64 * ldb;
    ushort_t* AsW0 = &As[(wid * 64) * 8];          // wave-uniform LDS bases
    ushort_t* AsW1 = &As[(256 + wid * 64) * 8];
    ushort_t* BsW0 = &Bs[(wid * 64) * 8];
    ushort_t* BsW1 = &Bs[(256 + wid * 64) * 8];

    const int fr = lane & 15;          // fragment row/col within 16
    const int kh = (lane >> 4) * 8;    // k offset within BK

    for (int k0 = 0; k0 < Ksz; k0 += BK) {
        gload_lds16(Ag0 + k0, AsW0);
        gload_lds16(Ag1 + k0, AsW1);
        gload_lds16(Bg0 + k0, BsW0);
        gload_lds16(Bg1 + k0, BsW1);
        __syncthreads();               // drains vmcnt before barrier

        bf16x8 af[4], bfv[4];
        #pragma unroll
        for (int i = 0; i < 4; ++i) {
            af[i]  = *(const bf16x8*)&As[(wm + i * 16 + fr) * BK + kh];
            bfv[i] = *(const bf16x8*)&Bs[(wn + i * 16 + fr) * BK + kh];
        }
        #pragma unroll
        for (int i = 0; i < 4; ++i)
            #pragma unroll
            for (int j = 0; j < 4; ++j)
                acc[i][j] = __builtin_amdgcn_mfma_f32_16x16x32_bf16(
                    af[i], bfv[j], acc[i][j], 0, 0, 0);
        __syncthreads();
    }

    // C/D layout: col = lane&15, row = (lane>>4)*4 + reg
    const int cr = (lane >> 4) * 4;
    const int cc = lane & 15;
    float* Cf = (float*)Cv + (size_t)blockIdx.z * zstride;
    #pragma unroll
    for (int i = 0; i < 4; ++i)
        #pragma unroll
        for (int j = 0; j < 4; ++j) {
            const int col = bn + wn + j * 16 + cc;
            const int rowb = bm + wm + i * 16 + cr;
            #pragma unroll
            for (int jj = 0; jj < 4; ++jj) {
                const float val = alpha * acc[i][j][jj];
                if (STORE_BF16)
                    ((ushort_t*)Cv)[(size_t)(rowb + jj) * ldc + col] = f2bf(val);
                else
                    Cf[(size_t)(rowb + jj) * ldc + col] = val;
            }
        }
}

// ---------------------------------------------------------------------------
__global__ void f32_to_bf16_vec(const float* __restrict__ in,
                                ushort_t* __restrict__ out, int n8)
{
    const int i = blockIdx.x * 256 + threadIdx.x;
    if (i >= n8) return;
    const float4 a = ((const float4*)in)[2 * i];
    const float4 b = ((const float4*)in)[2 * i + 1];
    ushort8v o;
    o[0] = f2bf(a.x); o[1] = f2bf(a.y); o[2] = f2bf(a.z); o[3] = f2bf(a.w);
    o[4] = f2bf(b.x); o[5] = f2bf(b.y); o[6] = f2bf(b.z); o[7] = f2bf(b.w);
    ((ushort8v*)out)[i] = o;
}

// W[K][O] (f32) -> Wt[O][K] (bf16)
__global__ void transpose_to_bf16(const float* __restrict__ W,
                                  ushort_t* __restrict__ Wt, int K, int O)
{
    const int idx = blockIdx.x * 256 + threadIdx.x;
    if (idx >= K * O) return;
    const int i = idx % K;
    const int o = idx / K;
    Wt[idx] = f2bf(W[(size_t)i * O + o]);
}

// per-node dots from merged qk buffer (row stride 2*HID; k at offset HID)
__global__ __launch_bounds__(256) void node_dots(
    const ushort_t* __restrict__ qk,
    const float* __restrict__ Ek, const float* __restrict__ Eq,
    float* qk0, float* qk1, float* kq0, float* kq1, int HID)
{
    const int node = blockIdx.x;
    const int t = threadIdx.x;   // == HID == 256
    const ushort_t* row = qk + (size_t)node * (2 * HID);
    const float qv = bf2f(row[t]);
    const float kv = bf2f(row[HID + t]);
    float p0 = qv * Ek[t];
    float p1 = qv * Ek[HID + t];
    float p2 = kv * Eq[t];
    float p3 = kv * Eq[HID + t];
    #pragma unroll
    for (int off = 32; off > 0; off >>= 1) {
        p0 += __shfl_down(p0, off);
        p1 += __shfl_down(p1, off);
        p2 += __shfl_down(p2, off);
        p3 += __shfl_down(p3, off);
    }
    __shared__ float red[4][4];
    if ((t & 63) == 0) {
        const int w = t >> 6;
        red[w][0] = p0; red[w][1] = p1; red[w][2] = p2; red[w][3] = p3;
    }
    __syncthreads();
    if (t == 0) {
        qk0[node] = red[0][0] + red[1][0] + red[2][0] + red[3][0];
        qk1[node] = red[0][1] + red[1][1] + red[2][1] + red[3][1];
        kq0[node] = red[0][2] + red[1][2] + red[2][2] + red[3][2];
        kq1[node] = red[0][3] + red[1][3] + red[2][3] + red[3][3];
    }
}

__global__ void edge_bias_kernel(
    const int* __restrict__ ei, const float* __restrict__ attr,
    const float* __restrict__ qk0, const float* __restrict__ qk1,
    const float* __restrict__ kq0, const float* __restrict__ kq1,
    float* __restrict__ A, int E, int N,
    const float* __restrict__ ibp, const float* __restrict__ imp)
{
    const int e = blockIdx.x * blockDim.x + threadIdx.x;
    if (e >= E) return;
    const int src = ei[e];
    const int dst = ei[E + e];
    const float s = 1.f / (1.f + __expf(-(attr[e] - ibp[0]) * imp[0]));
    const float bias = s * qk0[src] + (1.f - s) * qk1[src]
                     + s * kq0[dst] + (1.f - s) * kq1[dst];
    atomicAdd(&A[(size_t)src * N + dst], bias);
}

// row softmax: read f32 logits, write bf16 probs. N==4096, 256 threads.
__global__ __launch_bounds__(256) void softmax_rows_bf16(
    const float* __restrict__ A, ushort_t* __restrict__ P, int N, float scale)
{
    const int row = blockIdx.x;
    const float* a = A + (size_t)row * N;
    ushort_t* p = P + (size_t)row * N;
    const int t = threadIdx.x;
    float4 vals[4];
    float mx = -1e30f;
    #pragma unroll
    for (int u = 0; u < 4; ++u) {
        float4 vv = ((const float4*)a)[t + u * 256];
        vv.x *= scale; vv.y *= scale; vv.z *= scale; vv.w *= scale;
        vals[u] = vv;
        mx = fmaxf(mx, fmaxf(fmaxf(vv.x, vv.y), fmaxf(vv.z, vv.w)));
    }
    __shared__ float red[4];
    #pragma unroll
    for (int off = 32; off > 0; off >>= 1) mx = fmaxf(mx, __shfl_down(mx, off));
    if ((t & 63) == 0) red[t >> 6] = mx;
    __syncthreads();
    const float m = fmaxf(fmaxf(red[0], red[1]), fmaxf(red[2], red[3]));
    __syncthreads();
    float sum = 0.f;
    #pragma unroll
    for (int u = 0; u < 4; ++u) {
        vals[u].x = __expf(vals[u].x - m);
        vals[u].y = __expf(vals[u].y - m);
        vals[u].z = __expf(vals[u].z - m);
        vals[u].w = __expf(vals[u].w - m);
        sum += vals[u].x + vals[u].y + vals[u].z + vals[u].w;
    }
    #pragma unroll
    for (int off = 32; off > 0; off >>= 1) sum += __shfl_down(sum, off);
    if ((t & 63) == 0) red[t >> 6] = sum;
    __syncthreads();
    const float inv = 1.f / (red[0] + red[1] + red[2] + red[3]);
    #pragma unroll
    for (int u = 0; u < 4; ++u) {
        ushort4v o;
        o[0] = f2bf(vals[u].x * inv);
        o[1] = f2bf(vals[u].y * inv);
        o[2] = f2bf(vals[u].z * inv);
        o[3] = f2bf(vals[u].w * inv);
        ((ushort4v*)p)[t + u * 256] = o;
    }
}

__global__ void zero_kernel(float* __restrict__ p, int n)
{
    const int i = blockIdx.x * blockDim.x + threadIdx.x;
    if (i < n) p[i] = 0.f;
}

__global__ void edge_coeff_kernel(
    const int* __restrict__ ei, const float* __restrict__ attr,
    const ushort_t* __restrict__ P, float* __restrict__ c0, float* __restrict__ c1,
    int E, int N, const float* __restrict__ ibp, const float* __restrict__ imp)
{
    const int e = blockIdx.x * blockDim.x + threadIdx.x;
    if (e >= E) return;
    const int src = ei[e];
    const int dst = ei[E + e];
    const float s = 1.f / (1.f + __expf(-(attr[e] - ibp[0]) * imp[0]));
    const float pv = bf2f(P[(size_t)src * N + dst]);
    atomicAdd(&c0[src], pv * s);
    atomicAdd(&c1[src], pv * (1.f - s));
}

// out = sum_z parts[z] + c0[i]*Ev0 + c1[i]*Ev1  (float4-vectorized)
__global__ void reduce_add_rv_kernel(
    const float* __restrict__ parts, float* __restrict__ out,
    const float* __restrict__ c0, const float* __restrict__ c1,
    const float* __restrict__ Ev, int FEAT, size_t zstride, int nz)
{
    const int i4 = blockIdx.x * 256 + threadIdx.x;   // float4 index
    const int F4 = FEAT / 4;
    const int node = i4 / F4;
    const int f4 = i4 % F4;
    float4 acc = ((const float4*)parts)[i4];
    for (int z = 1; z < nz; ++z) {
        const float4 p = *(const float4*)(parts + (size_t)z * zstride + (size_t)i4 * 4);
        acc.x += p.x; acc.y += p.y; acc.z += p.z; acc.w += p.w;
    }
    const float a0 = c0[node], a1 = c1[node];
    const float4 e0 = ((const float4*)Ev)[f4];
    const float4 e1 = ((const float4*)Ev)[F4 + f4];
    acc.x += a0 * e0.x + a1 * e1.x;
    acc.y += a0 * e0.y + a1 * e1.y;
    acc.z += a0 * e0.z + a1 * e1.z;
    acc.w += a0 * e0.w + a1 * e1.w;
    ((float4*)out)[i4] = acc;
}

// ---------------------------------------------------------------------------
extern "C" void kernel_launch(void* const* d_in, const int* in_sizes, int n_in,
                              void* d_out, int out_size, void* d_ws, size_t ws_size,
                              hipStream_t stream)
{
    const float* x    = (const float*)d_in[0];
    const int*   ei   = (const int*)d_in[1];
    const float* attr = (const float*)d_in[2];
    const float* Wk   = (const float*)d_in[3];
    const float* Wq   = (const float*)d_in[4];
    const float* Wv   = (const float*)d_in[5];
    const float* Ek   = (const float*)d_in[6];
    const float* Eq   = (const float*)d_in[7];
    const float* Ev   = (const float*)d_in[8];
    const float* ib   = (const float*)d_in[9];
    const float* im   = (const float*)d_in[10];
    float* out = (float*)d_out;

    const int FEAT = (int)lroundf(sqrtf((float)in_sizes[5]));   // 512
    const int HID  = in_sizes[3] / FEAT;                        // 256
    const int N    = in_sizes[0] / FEAT;                        // 4096
    const int E    = in_sizes[2];                               // 131072

    char* w = (char*)d_ws;
    size_t o = 0;
    ushort_t* xb   = (ushort_t*)(w + o); o += (size_t)N * FEAT * 2;       // 4 MB
    ushort_t* Wqkt = (ushort_t*)(w + o); o += (size_t)2 * HID * FEAT * 2; // 512 KB ([2*HID][FEAT])
    ushort_t* Wvt  = (ushort_t*)(w + o); o += (size_t)FEAT * FEAT * 2;    // 512 KB
    ushort_t* qkb  = (ushort_t*)(w + o); o += (size_t)N * 2 * HID * 2;    // 4 MB ([N][2*HID])
    ushort_t* vTb  = (ushort_t*)(w + o); o += (size_t)FEAT * N * 2;       // 4 MB
    float*    Abuf = (float*)(w + o);    o += (size_t)N * N * 4;          // 64 MB
    ushort_t* Pb   = (ushort_t*)(w + o); o += (size_t)N * N * 2;          // 32 MB
    float*    qk0  = (float*)(w + o);    o += (size_t)N * 4;
    float*    qk1  = (float*)(w + o);    o += (size_t)N * 4;
    float*    kq0  = (float*)(w + o);    o += (size_t)N * 4;
    float*    kq1  = (float*)(w + o);    o += (size_t)N * 4;
    float*    c0   = (float*)(w + o);    o += (size_t)N * 4;
    float*    c1   = (float*)(w + o);    o += (size_t)N * 4;   // contiguous w/ c0
    float*    pvpart = Abuf;   // logits dead after softmax; 4 x 8 MB partials fit in 64 MB

    const dim3 blk(256);
    const int NZ = 4;                  // split-K chunks for P@V
    const int Kchunk = N / NZ;         // 1024

    // bf16 conversions
    f32_to_bf16_vec<<<(N * FEAT / 8 + 255) / 256, blk, 0, stream>>>(x, xb, N * FEAT / 8);
    transpose_to_bf16<<<(FEAT * HID + 255) / 256, blk, 0, stream>>>(Wq, Wqkt, FEAT, HID);
    transpose_to_bf16<<<(FEAT * HID + 255) / 256, blk, 0, stream>>>(Wk, Wqkt + (size_t)HID * FEAT, FEAT, HID);
    transpose_to_bf16<<<(FEAT * FEAT + 255) / 256, blk, 0, stream>>>(Wv, Wvt, FEAT, FEAT);

    // merged q|k projection: qkb[N][2*HID] = xb @ Wqkt^T
    gemm_nt_mfma<true><<<dim3(2 * HID / 128, N / 128), blk, 0, stream>>>(
        xb, Wqkt, qkb, FEAT, FEAT, 2 * HID, FEAT, 1.f, 0);
    // vT projection: vTb[FEAT][N] = Wvt @ xb^T
    gemm_nt_mfma<true><<<dim3(N / 128, FEAT / 128), blk, 0, stream>>>(
        Wvt, xb, vTb, FEAT, FEAT, N, FEAT, 1.f, 0);

    // per-node embedding dots
    node_dots<<<N, blk, 0, stream>>>(qkb, Ek, Eq, qk0, qk1, kq0, kq1, HID);

    // A = 2 * q k^T  (f32)
    gemm_nt_mfma<false><<<dim3(N / 128, N / 128), blk, 0, stream>>>(
        qkb, qkb + HID, Abuf, 2 * HID, 2 * HID, N, HID, 2.f, 0);

    // += per-edge bias
    edge_bias_kernel<<<(E + 255) / 256, blk, 0, stream>>>(ei, attr, qk0, qk1, kq0, kq1,
                                                          Abuf, E, N, ib, im);

    // P = softmax(A / sqrt(FEAT)) -> bf16
    softmax_rows_bf16<<<N, blk, 0, stream>>>(Abuf, Pb, N, 1.f / sqrtf((float)FEAT));

    // edge coefficients
    zero_kernel<<<(2 * N + 255) / 256, blk, 0, stream>>>(c0, 2 * N);
    edge_coeff_kernel<<<(E + 255) / 256, blk, 0, stream>>>(ei, attr, Pb, c0, c1, E, N, ib, im);

    // out partials: pvpart[z] = P[:, zK:(z+1)K] @ v[zK:(z+1)K, :]
    gemm_nt_mfma<false><<<dim3(FEAT / 128, N / 128, NZ), blk, 0, stream>>>(
        Pb, vTb, pvpart, N, N, FEAT, Kchunk, 1.f, (size_t)N * FEAT);

    // out = sum_z partials + c0[i]*Ev0 + c1[i]*Ev1
    reduce_add_rv_kernel<<<(N * FEAT / 4 + 255) / 256, blk, 0, stream>>>(
        pvpart, out, c0, c1, Ev, FEAT, (size_t)N * FEAT, NZ);
}